// Round 3
// baseline (289.538 us; speedup 1.0000x reference)
//
#include <hip/hip_runtime.h>

#define SQ3F 0.35355339059327379f

// Forward 2x2x2 Haar butterfly. v index = z*4+y*2+x. o index = fz*4+fy*2+fx.
__device__ __forceinline__ void haar_fwd(const float v[8], float o[8]) {
    float ax[8];
#pragma unroll
    for (int i = 0; i < 4; ++i) {
        float a = v[2 * i], b = v[2 * i + 1];
        ax[2 * i]     = a + b;
        ax[2 * i + 1] = b - a;
    }
    float ay[8];
#pragma unroll
    for (int z = 0; z < 2; ++z)
#pragma unroll
        for (int bx = 0; bx < 2; ++bx) {
            float a = ax[z * 4 + bx], b = ax[z * 4 + 2 + bx];
            ay[z * 4 + bx]     = a + b;
            ay[z * 4 + 2 + bx] = b - a;
        }
#pragma unroll
    for (int j = 0; j < 4; ++j) {
        float a = ay[j], b = ay[4 + j];
        o[j]     = (a + b) * SQ3F;
        o[4 + j] = (b - a) * SQ3F;
    }
}

// Inverse Haar. t index = fz*4+fy*2+fx. o index = z*4+y*2+x.
__device__ __forceinline__ void haar_inv(const float t[8], float o[8]) {
    float az[8];
#pragma unroll
    for (int j = 0; j < 4; ++j) {
        float lo = t[j], hi = t[4 + j];
        az[j]     = lo + hi;
        az[4 + j] = lo - hi;
    }
    float ay[8];
#pragma unroll
    for (int z = 0; z < 2; ++z)
#pragma unroll
        for (int bx = 0; bx < 2; ++bx) {
            float lo = az[z * 4 + bx], hi = az[z * 4 + 2 + bx];
            ay[z * 4 + bx]     = lo + hi;
            ay[z * 4 + 2 + bx] = lo - hi;
        }
#pragma unroll
    for (int i = 0; i < 4; ++i) {
        float lo = ay[2 * i], hi = ay[2 * i + 1];
        o[2 * i]     = (lo + hi) * SQ3F;
        o[2 * i + 1] = (lo - hi) * SQ3F;
    }
}

// ===================== Fused level-0: DWT + depthwise conv + soft ==========
// Grid: 64 ch x 4 z-slabs x 2 band-halves = 512 blocks, 512 threads.
// LDS: 3 rolling DWT plane slots x 4 bands x 32 rows x 34 cols (cols -1..32,
// zero-padded edges). Conv reads straight from LDS; raw LL band (bh==0,f==0)
// is written to `ll` for level 1.
#define L0_PAD 34
__global__ __launch_bounds__(512, 2) void fused_l0_k(
    const float* __restrict__ x, const float* __restrict__ wt,
    const float* __restrict__ wscale, const float* __restrict__ lambd_p,
    float* __restrict__ t0, float* __restrict__ ll) {
    __shared__ float bp[3][4][32][L0_PAD];
    int bx   = blockIdx.x;
    int bh   = bx & 1;
    int slab = (bx >> 1) & 3;
    int c    = bx >> 3;
    int z0   = slab * 8;
    int tid  = threadIdx.x;

    // zero the pad columns (col -1 -> idx 0, col 32 -> idx 33); never rewritten
    for (int i = tid; i < 3 * 4 * 32; i += 512) {
        float* row = &bp[0][0][0][0] + i * L0_PAD;
        row[0]  = 0.f;
        row[33] = 0.f;
    }

    // conv mapping: band f (wave-uniform), row cty, 8-wide x run at cx0i
    int fl   = tid >> 7;  // 0..3
    int f    = __builtin_amdgcn_readfirstlane(bh * 4 + fl);
    int u    = tid & 127;
    int cty  = u >> 2;
    int cx0i = (u & 3) * 8;
    int cc   = c * 8 + f;
    float wv[27];
    const float* wp = wt + cc * 27;
#pragma unroll
    for (int k = 0; k < 27; ++k) wv[k] = wp[k];
    float lam = *lambd_p;
    float sc  = wscale[cc];
    bool hf   = (f != 0);

    const float* xc = x + ((long)c << 18);

    auto compute_plane = [&](int p, int slot) {
#pragma unroll
        for (int cell2 = 0; cell2 < 2; ++cell2) {
            int cell = tid + cell2 * 512;
            int y = cell >> 5, xx = cell & 31;
            float v[8];
            bool ok = (unsigned)p < 32u;
            if (ok) {
#pragma unroll
                for (int z = 0; z < 2; ++z)
#pragma unroll
                    for (int yy = 0; yy < 2; ++yy) {
                        float2 q = *(const float2*)(xc + (((2 * p + z) << 6) +
                                                          (2 * y + yy)) * 64 + 2 * xx);
                        v[z * 4 + yy * 2]     = q.x;
                        v[z * 4 + yy * 2 + 1] = q.y;
                    }
            } else {
#pragma unroll
                for (int k = 0; k < 8; ++k) v[k] = 0.f;
            }
            float o[8];
            haar_fwd(v, o);
#pragma unroll
            for (int k = 0; k < 4; ++k) bp[slot][k][y][xx + 1] = o[bh * 4 + k];
            if (bh == 0 && ok && (unsigned)(p - z0) < 8u)
                ll[(c << 15) + (p << 10) + cell] = o[0];
        }
    };

    compute_plane(z0 - 1, (z0 + 2) % 3);
    compute_plane(z0, z0 % 3);
    __syncthreads();

    for (int zb = z0; zb < z0 + 8; ++zb) {
        compute_plane(zb + 1, (zb + 1) % 3);
        __syncthreads();

        float acc[8] = {0.f, 0.f, 0.f, 0.f, 0.f, 0.f, 0.f, 0.f};
#pragma unroll
        for (int dz = 0; dz < 3; ++dz) {
            int slot = (zb + 2 + dz) % 3;  // plane zb-1+dz
#pragma unroll
            for (int dy = 0; dy < 3; ++dy) {
                int yy = cty - 1 + dy;
                if ((unsigned)yy < 32u) {
                    float r[10];
#pragma unroll
                    for (int k = 0; k < 10; ++k) r[k] = bp[slot][fl][yy][cx0i + k];
#pragma unroll
                    for (int dx = 0; dx < 3; ++dx) {
                        float wgt = wv[dz * 9 + dy * 3 + dx];
#pragma unroll
                        for (int j = 0; j < 8; ++j) acc[j] += r[dx + j] * wgt;
                    }
                }
            }
        }
        float res[8];
#pragma unroll
        for (int j = 0; j < 8; ++j) {
            float t = acc[j];
            if (hf) {
                float a = fabsf(t) - lam;
                t       = a > 0.f ? copysignf(a, t) : 0.f;
            }
            res[j] = t * sc;
        }
        float* op = t0 + ((long)cc << 15) + (zb << 10) + cty * 32 + cx0i;
        *(float4*)(op)     = float4{res[0], res[1], res[2], res[3]};
        *(float4*)(op + 4) = float4{res[4], res[5], res[6], res[7]};
        __syncthreads();
    }
}

// ===================== Level-1 kernels (as round 2, verified) ==============
template <int SO>
__global__ __launch_bounds__(256) void dwt3_k(const float* __restrict__ in,
                                              int inChStride,
                                              float* __restrict__ out) {
    constexpr int SI = SO * 2;
    int idx = blockIdx.x * 256 + threadIdx.x;
    int w = idx % SO;
    int h = (idx / SO) % SO;
    int d = (idx / (SO * SO)) % SO;
    int c = idx / (SO * SO * SO);
    const float* ip = in + (long)c * inChStride;
    float v[8];
#pragma unroll
    for (int z = 0; z < 2; ++z)
#pragma unroll
        for (int y = 0; y < 2; ++y) {
            const float2 p =
                *(const float2*)(ip + ((2 * d + z) * SI + (2 * h + y)) * SI + 2 * w);
            v[z * 4 + y * 2]     = p.x;
            v[z * 4 + y * 2 + 1] = p.y;
        }
    float o[8];
    haar_fwd(v, o);
    int s = (d * SO + h) * SO + w;
#pragma unroll
    for (int f = 0; f < 8; ++f) out[(c * 8 + f) * (SO * SO * SO) + s] = o[f];
}

template <int S, int PH>
__device__ __forceinline__ void conv_step(const float* __restrict__ ip, int zo,
                                          int ty, int x0,
                                          const float* __restrict__ wv,
                                          float win[3][3][6], float lam, float sc,
                                          bool hf, float* __restrict__ op) {
    constexpr int sPrev = (PH + 2) % 3;
    constexpr int sCur  = PH;
    constexpr int sNext = (PH + 1) % 3;
    {
        int zz = zo + 1;
        bool zok = zz < S;
        const float* pp = ip + zz * S * S;
#pragma unroll
        for (int dy = 0; dy < 3; ++dy) {
            int yy  = ty - 1 + dy;
            bool yok = zok && ((unsigned)yy < (unsigned)S);
            const float* rp = pp + yy * S;
            win[sNext][dy][0] = (yok && x0 > 0) ? rp[x0 - 1] : 0.f;
            float4 m = yok ? *(const float4*)(rp + x0) : float4{0.f, 0.f, 0.f, 0.f};
            win[sNext][dy][1] = m.x;
            win[sNext][dy][2] = m.y;
            win[sNext][dy][3] = m.z;
            win[sNext][dy][4] = m.w;
            win[sNext][dy][5] = (yok && (x0 + 4 < S)) ? rp[x0 + 4] : 0.f;
        }
    }
    float acc[4] = {0.f, 0.f, 0.f, 0.f};
#pragma unroll
    for (int dz = 0; dz < 3; ++dz) {
        const float(*wp)[6] = (dz == 0) ? win[sPrev] : (dz == 1) ? win[sCur] : win[sNext];
#pragma unroll
        for (int dy = 0; dy < 3; ++dy)
#pragma unroll
            for (int dx = 0; dx < 3; ++dx) {
                float wgt = wv[dz * 9 + dy * 3 + dx];
#pragma unroll
                for (int j = 0; j < 4; ++j) acc[j] += wp[dy][dx + j] * wgt;
            }
    }
    float4 r;
    float* rr = (float*)&r;
#pragma unroll
    for (int j = 0; j < 4; ++j) {
        float t = acc[j];
        if (hf) {
            float a = fabsf(t) - lam;
            t       = a > 0.f ? copysignf(a, t) : 0.f;
        }
        rr[j] = t * sc;
    }
    *(float4*)(op + (zo * S + ty) * S + x0) = r;
}

template <int S, int CPB>
__global__ __launch_bounds__(256) void dwconv_soft_roll_k(
    const float* __restrict__ in, const float* __restrict__ wt,
    const float* __restrict__ wscale, const float* __restrict__ lambd_p,
    float* __restrict__ out) {
    constexpr int TX = S / 4;
    int tid = threadIdx.x;
    int tx  = tid % TX;
    int ty  = (tid / TX) % S;
    int cs  = tid / (TX * S);
    int cc  = blockIdx.x * CPB + cs;
    const float* ip = in + (long)cc * (S * S * S);
    float* op       = out + (long)cc * (S * S * S);
    float wv[27];
#pragma unroll
    for (int k = 0; k < 27; ++k) wv[k] = wt[cc * 27 + k];
    float lam = *lambd_p;
    float sc  = wscale[cc];
    bool hf   = (cc & 7) != 0;
    int x0    = 4 * tx;

    float win[3][3][6];
#pragma unroll
    for (int a = 0; a < 3; ++a)
#pragma unroll
        for (int b = 0; b < 3; ++b)
#pragma unroll
            for (int k = 0; k < 6; ++k) win[a][b][k] = 0.f;
    {
#pragma unroll
        for (int dy = 0; dy < 3; ++dy) {
            int yy  = ty - 1 + dy;
            bool yok = (unsigned)yy < (unsigned)S;
            const float* rp = ip + yy * S;
            win[0][dy][0] = (yok && x0 > 0) ? rp[x0 - 1] : 0.f;
            float4 m = yok ? *(const float4*)(rp + x0) : float4{0.f, 0.f, 0.f, 0.f};
            win[0][dy][1] = m.x;
            win[0][dy][2] = m.y;
            win[0][dy][3] = m.z;
            win[0][dy][4] = m.w;
            win[0][dy][5] = (yok && (x0 + 4 < S)) ? rp[x0 + 4] : 0.f;
        }
    }
#pragma unroll 1
    for (int zb = 0; zb < S; zb += 3) {
        conv_step<S, 0>(ip, zb, ty, x0, wv, win, lam, sc, hf, op);
        if (zb + 1 < S) conv_step<S, 1>(ip, zb + 1, ty, x0, wv, win, lam, sc, hf, op);
        if (zb + 2 < S) conv_step<S, 2>(ip, zb + 2, ty, x0, wv, win, lam, sc, hf, op);
    }
}

template <int SI>
__global__ __launch_bounds__(256) void idwt_add_k(const float* __restrict__ t,
                                                  float* __restrict__ dst,
                                                  int dstChStride) {
    int idx = blockIdx.x * 256 + threadIdx.x;
    int w = idx % SI, h = (idx / SI) % SI, d = (idx / (SI * SI)) % SI,
        c = idx / (SI * SI * SI);
    int s = (d * SI + h) * SI + w;
    float tf[8], o[8];
#pragma unroll
    for (int f = 0; f < 8; ++f) tf[f] = t[(c * 8 + f) * (SI * SI * SI) + s];
    haar_inv(tf, o);
    float* dp = dst + (long)c * dstChStride;
    constexpr int SD = SI * 2;
#pragma unroll
    for (int z = 0; z < 2; ++z)
#pragma unroll
        for (int y = 0; y < 2; ++y) {
            float* q = dp + ((2 * d + z) * SD + (2 * h + y)) * SD + 2 * w;
            q[0] += o[z * 4 + y * 2];
            q[1] += o[z * 4 + y * 2 + 1];
        }
}

// ===================== Final: LDS-tiled base conv + level-0 IDWT ===========
// Block = 256 threads = 4x8x8 cubes tile; x patch 10x18x18 staged in LDS.
__global__ __launch_bounds__(256) void final_tile_k(const float* __restrict__ x,
                                                    const float* __restrict__ t0,
                                                    const float* __restrict__ bw,
                                                    const float* __restrict__ bb,
                                                    const float* __restrict__ bscale,
                                                    float* __restrict__ out) {
    __shared__ float xs[10 * 18 * 18];
    int bx  = blockIdx.x;
    int c   = bx >> 7;
    int rem = bx & 127;
    int dt = rem >> 4, ht = (rem >> 2) & 3, wtl = rem & 3;
    int zb = 8 * dt - 1, yb = 16 * ht - 1, xbg = 16 * wtl - 1;
    const float* xc = x + ((long)c << 18);
    for (int i = threadIdx.x; i < 3240; i += 256) {
        int pz = i / 324;
        int r  = i - pz * 324;
        int py = r / 18;
        int px = r - py * 18;
        int zg = zb + pz, yg = yb + py, xg = xbg + px;
        bool ok = ((unsigned)zg < 64u) && ((unsigned)yg < 64u) && ((unsigned)xg < 64u);
        xs[i] = ok ? xc[((zg << 6) + yg) * 64 + xg] : 0.f;
    }
    const float* wp0 = bw + c * 27;
    float wv[27];
#pragma unroll
    for (int k = 0; k < 27; ++k) wv[k] = wp0[k];
    float bias = bb[c], scl = bscale[c];
    __syncthreads();

    int tw = threadIdx.x & 7, th = (threadIdx.x >> 3) & 7, td = threadIdx.x >> 6;
    int d = dt * 4 + td, h = ht * 8 + th, w = wtl * 8 + tw;
    int cell = (d << 10) + (h << 5) + w;

    float tf[8];
#pragma unroll
    for (int f = 0; f < 8; ++f) tf[f] = t0[((c * 8 + f) << 15) + cell];
    float contrib[8];
    haar_inv(tf, contrib);

    float p[4][4][4];
#pragma unroll
    for (int pz = 0; pz < 4; ++pz)
#pragma unroll
        for (int py = 0; py < 4; ++py)
#pragma unroll
            for (int px = 0; px < 4; ++px)
                p[pz][py][px] =
                    xs[(2 * td + pz) * 324 + (2 * th + py) * 18 + 2 * tw + px];

#pragma unroll
    for (int oz = 0; oz < 2; ++oz)
#pragma unroll
        for (int oy = 0; oy < 2; ++oy) {
            float r2[2];
#pragma unroll
            for (int ox = 0; ox < 2; ++ox) {
                float acc = 0.f;
#pragma unroll
                for (int kz = 0; kz < 3; ++kz)
#pragma unroll
                    for (int ky = 0; ky < 3; ++ky)
#pragma unroll
                        for (int kx = 0; kx < 3; ++kx)
                            acc += p[oz + kz][oy + ky][ox + kx] * wv[kz * 9 + ky * 3 + kx];
                r2[ox] = (acc + bias) * scl + contrib[oz * 4 + oy * 2 + ox];
            }
            *(float2*)(out + (((c << 6) + 2 * d + oz) * 64 + 2 * h + oy) * 64 + 2 * w) =
                float2{r2[0], r2[1]};
        }
}

extern "C" void kernel_launch(void* const* d_in, const int* in_sizes, int n_in,
                              void* d_out, int out_size, void* d_ws, size_t ws_size,
                              hipStream_t stream) {
    const float* x      = (const float*)d_in[0];
    const float* base_w = (const float*)d_in[1];
    const float* base_b = (const float*)d_in[2];
    const float* base_s = (const float*)d_in[3];
    const float* w0     = (const float*)d_in[4];
    const float* w1     = (const float*)d_in[5];
    const float* ws0    = (const float*)d_in[6];
    const float* ws1    = (const float*)d_in[7];
    const float* lambd  = (const float*)d_in[8];
    float* out = (float*)d_out;

    // Workspace (floats): ll 2.1M | t0 16.8M | cx1 2.1M | t1 2.1M  = ~92 MiB
    float* ll  = (float*)d_ws;
    float* t0  = ll + 2097152;
    float* cx1 = t0 + 16777216;
    float* t1  = cx1 + 2097152;

    // Level 0 fused: x -> t0 (conv'd, thresholded, scaled) + raw LL
    fused_l0_k<<<512, 512, 0, stream>>>(x, w0, ws0, lambd, t0, ll);
    // Level 1
    dwt3_k<16><<<1024, 256, 0, stream>>>(ll, 32768, cx1);
    dwconv_soft_roll_k<16, 4><<<128, 256, 0, stream>>>(cx1, w1, ws1, lambd, t1);
    idwt_add_k<16><<<1024, 256, 0, stream>>>(t1, t0, 8 * 32768);
    // Final
    final_tile_k<<<8192, 256, 0, stream>>>(x, t0, base_w, base_b, base_s, out);
}

// Round 4
// 252.680 us; speedup vs baseline: 1.1459x; 1.1459x over previous
//
#include <hip/hip_runtime.h>

#define SQ3F 0.35355339059327379f

// Forward 2x2x2 Haar butterfly. v index = z*4+y*2+x. o index = fz*4+fy*2+fx.
__device__ __forceinline__ void haar_fwd(const float v[8], float o[8]) {
    float ax[8];
#pragma unroll
    for (int i = 0; i < 4; ++i) {
        float a = v[2 * i], b = v[2 * i + 1];
        ax[2 * i]     = a + b;
        ax[2 * i + 1] = b - a;
    }
    float ay[8];
#pragma unroll
    for (int z = 0; z < 2; ++z)
#pragma unroll
        for (int bx = 0; bx < 2; ++bx) {
            float a = ax[z * 4 + bx], b = ax[z * 4 + 2 + bx];
            ay[z * 4 + bx]     = a + b;
            ay[z * 4 + 2 + bx] = b - a;
        }
#pragma unroll
    for (int j = 0; j < 4; ++j) {
        float a = ay[j], b = ay[4 + j];
        o[j]     = (a + b) * SQ3F;
        o[4 + j] = (b - a) * SQ3F;
    }
}

// Inverse Haar. t index = fz*4+fy*2+fx. o index = z*4+y*2+x.
__device__ __forceinline__ void haar_inv(const float t[8], float o[8]) {
    float az[8];
#pragma unroll
    for (int j = 0; j < 4; ++j) {
        float lo = t[j], hi = t[4 + j];
        az[j]     = lo + hi;
        az[4 + j] = lo - hi;
    }
    float ay[8];
#pragma unroll
    for (int z = 0; z < 2; ++z)
#pragma unroll
        for (int bx = 0; bx < 2; ++bx) {
            float lo = az[z * 4 + bx], hi = az[z * 4 + 2 + bx];
            ay[z * 4 + bx]     = lo + hi;
            ay[z * 4 + 2 + bx] = lo - hi;
        }
#pragma unroll
    for (int i = 0; i < 4; ++i) {
        float lo = ay[2 * i], hi = ay[2 * i + 1];
        o[2 * i]     = (lo + hi) * SQ3F;
        o[2 * i + 1] = (lo - hi) * SQ3F;
    }
}

// ============ Fused level-0: DWT + depthwise conv + soft-threshold =========
// Grid: bx = c*8 + slab. Block covers z-cells z0..z0+3 (z0 = slab*4) for all
// 8 bands of channel c. Single LDS plane slot (8 bands x 32 rows x 35 cols,
// col 0 = x=-1 pad, col 33 = x=32 pad, stride 35 => conflict-free).
// z-direction handled by register ring acc[3][16]: each DWT plane is read
// from LDS once and folded into the 3 pending z-outputs.
__global__ __launch_bounds__(512, 4) void fused_l0_k(
    const float* __restrict__ x, const float* __restrict__ wt,
    const float* __restrict__ wscale, const float* __restrict__ lambd_p,
    float* __restrict__ t0, float* __restrict__ ll) {
    __shared__ float pl[8][32][35];
    int bx   = blockIdx.x;
    int slab = bx & 7;
    int c    = bx >> 3;
    int z0   = slab * 4;
    int tid  = threadIdx.x;

    // zero the x-pad columns once (512 pad slots, one per thread)
    {
        int fi   = tid >> 6;
        int rowi = (tid >> 1) & 31;
        pl[fi][rowi][(tid & 1) * 33] = 0.f;
    }

    int f    = __builtin_amdgcn_readfirstlane(tid >> 6);  // band, wave-uniform
    int lane = tid & 63;
    int cty  = lane >> 1;         // conv row 0..31
    int cx0i = (lane & 1) * 16;   // 16-wide x chunk
    int cc   = c * 8 + f;
    float wv[27];
    const float* wp = wt + cc * 27;
#pragma unroll
    for (int k = 0; k < 27; ++k) wv[k] = wp[k];
    float lam = *lambd_p;
    float sc  = wscale[cc];

    const float* xc = x + ((long)c << 18);

    float acc[3][16];
#pragma unroll
    for (int s = 0; s < 3; ++s)
#pragma unroll
        for (int j = 0; j < 16; ++j) acc[s][j] = 0.f;

    // pp fully unrolled so acc/ring indices are compile-time constants.
#pragma unroll
    for (int pp = 0; pp < 6; ++pp) {
        int p       = z0 - 1 + pp;
        bool pvalid = (p >= 0) && (p <= 31);  // wave-uniform
        __syncthreads();
        if (pvalid) {
            // DWT plane p -> LDS (1024 cells, 2 per thread)
#pragma unroll
            for (int half = 0; half < 2; ++half) {
                int cell = tid + half * 512;
                int y = cell >> 5, xx = cell & 31;
                float v[8];
#pragma unroll
                for (int z = 0; z < 2; ++z)
#pragma unroll
                    for (int yy = 0; yy < 2; ++yy) {
                        float2 q = *(const float2*)(xc + (((2 * p + z) << 6) +
                                                          (2 * y + yy)) * 64 + 2 * xx);
                        v[z * 4 + yy * 2]     = q.x;
                        v[z * 4 + yy * 2 + 1] = q.y;
                    }
                float o[8];
                haar_fwd(v, o);
#pragma unroll
                for (int k = 0; k < 8; ++k) pl[k][y][xx + 1] = o[k];
                if (pp >= 1 && pp <= 4)  // interior plane: owns ll write
                    ll[(c << 15) + (p << 10) + cell] = o[0];
            }
        }
        __syncthreads();
        if (pvalid) {
            // fold plane p into pending outputs zc = p+1-dz (rel = pp-dz)
#pragma unroll
            for (int dy = 0; dy < 3; ++dy) {
                int yy = cty - 1 + dy;
                if ((unsigned)yy < 32u) {
                    float r[18];
#pragma unroll
                    for (int k = 0; k < 18; ++k) r[k] = pl[f][yy][cx0i + k];
#pragma unroll
                    for (int dz = 0; dz < 3; ++dz) {
                        constexpr int unused = 0; (void)unused;
                        int rel = pp - dz;
                        if (rel >= 0 && rel <= 3) {  // compile-time
                            int s = rel % 3;         // compile-time
#pragma unroll
                            for (int dx = 0; dx < 3; ++dx) {
                                float wgt = wv[dz * 9 + dy * 3 + dx];
#pragma unroll
                                for (int j = 0; j < 16; ++j)
                                    acc[s][j] += r[dx + j] * wgt;
                            }
                        }
                    }
                }
            }
        }
        // finalize output zc = p-1 (rel = pp-2) — needs planes p-2..p done
        {
            int rel = pp - 2;
            if (rel >= 0 && rel <= 3) {  // compile-time
                int zc = z0 + rel;
                // for slab 7, zc=31 finalizes at pp=5 even though p=32 skipped
                int s = rel % 3;  // compile-time
                float res[16];
#pragma unroll
                for (int j = 0; j < 16; ++j) {
                    float t = acc[s][j];
                    if (f != 0) {
                        float a = fabsf(t) - lam;
                        t       = a > 0.f ? copysignf(a, t) : 0.f;
                    }
                    res[j]    = t * sc;
                    acc[s][j] = 0.f;
                }
                float* op = t0 + ((long)cc << 15) + (zc << 10) + cty * 32 + cx0i;
#pragma unroll
                for (int q = 0; q < 4; ++q)
                    *(float4*)(op + q * 4) = float4{res[q * 4], res[q * 4 + 1],
                                                    res[q * 4 + 2], res[q * 4 + 3]};
            }
        }
    }
}

// ===================== Level-1 kernels (R2-verified) =======================
template <int SO>
__global__ __launch_bounds__(256) void dwt3_k(const float* __restrict__ in,
                                              int inChStride,
                                              float* __restrict__ out) {
    constexpr int SI = SO * 2;
    int idx = blockIdx.x * 256 + threadIdx.x;
    int w = idx % SO;
    int h = (idx / SO) % SO;
    int d = (idx / (SO * SO)) % SO;
    int c = idx / (SO * SO * SO);
    const float* ip = in + (long)c * inChStride;
    float v[8];
#pragma unroll
    for (int z = 0; z < 2; ++z)
#pragma unroll
        for (int y = 0; y < 2; ++y) {
            const float2 p =
                *(const float2*)(ip + ((2 * d + z) * SI + (2 * h + y)) * SI + 2 * w);
            v[z * 4 + y * 2]     = p.x;
            v[z * 4 + y * 2 + 1] = p.y;
        }
    float o[8];
    haar_fwd(v, o);
    int s = (d * SO + h) * SO + w;
#pragma unroll
    for (int f = 0; f < 8; ++f) out[(c * 8 + f) * (SO * SO * SO) + s] = o[f];
}

template <int S, int PH>
__device__ __forceinline__ void conv_step(const float* __restrict__ ip, int zo,
                                          int ty, int x0,
                                          const float* __restrict__ wv,
                                          float win[3][3][6], float lam, float sc,
                                          bool hf, float* __restrict__ op) {
    constexpr int sPrev = (PH + 2) % 3;
    constexpr int sCur  = PH;
    constexpr int sNext = (PH + 1) % 3;
    {
        int zz = zo + 1;
        bool zok = zz < S;
        const float* pp = ip + zz * S * S;
#pragma unroll
        for (int dy = 0; dy < 3; ++dy) {
            int yy  = ty - 1 + dy;
            bool yok = zok && ((unsigned)yy < (unsigned)S);
            const float* rp = pp + yy * S;
            win[sNext][dy][0] = (yok && x0 > 0) ? rp[x0 - 1] : 0.f;
            float4 m = yok ? *(const float4*)(rp + x0) : float4{0.f, 0.f, 0.f, 0.f};
            win[sNext][dy][1] = m.x;
            win[sNext][dy][2] = m.y;
            win[sNext][dy][3] = m.z;
            win[sNext][dy][4] = m.w;
            win[sNext][dy][5] = (yok && (x0 + 4 < S)) ? rp[x0 + 4] : 0.f;
        }
    }
    float acc[4] = {0.f, 0.f, 0.f, 0.f};
#pragma unroll
    for (int dz = 0; dz < 3; ++dz) {
        const float(*wp)[6] = (dz == 0) ? win[sPrev] : (dz == 1) ? win[sCur] : win[sNext];
#pragma unroll
        for (int dy = 0; dy < 3; ++dy)
#pragma unroll
            for (int dx = 0; dx < 3; ++dx) {
                float wgt = wv[dz * 9 + dy * 3 + dx];
#pragma unroll
                for (int j = 0; j < 4; ++j) acc[j] += wp[dy][dx + j] * wgt;
            }
    }
    float4 r;
    float* rr = (float*)&r;
#pragma unroll
    for (int j = 0; j < 4; ++j) {
        float t = acc[j];
        if (hf) {
            float a = fabsf(t) - lam;
            t       = a > 0.f ? copysignf(a, t) : 0.f;
        }
        rr[j] = t * sc;
    }
    *(float4*)(op + (zo * S + ty) * S + x0) = r;
}

template <int S, int CPB>
__global__ __launch_bounds__(256) void dwconv_soft_roll_k(
    const float* __restrict__ in, const float* __restrict__ wt,
    const float* __restrict__ wscale, const float* __restrict__ lambd_p,
    float* __restrict__ out) {
    constexpr int TX = S / 4;
    int tid = threadIdx.x;
    int tx  = tid % TX;
    int ty  = (tid / TX) % S;
    int cs  = tid / (TX * S);
    int cc  = blockIdx.x * CPB + cs;
    const float* ip = in + (long)cc * (S * S * S);
    float* op       = out + (long)cc * (S * S * S);
    float wv[27];
#pragma unroll
    for (int k = 0; k < 27; ++k) wv[k] = wt[cc * 27 + k];
    float lam = *lambd_p;
    float sc  = wscale[cc];
    bool hf   = (cc & 7) != 0;
    int x0    = 4 * tx;

    float win[3][3][6];
#pragma unroll
    for (int a = 0; a < 3; ++a)
#pragma unroll
        for (int b = 0; b < 3; ++b)
#pragma unroll
            for (int k = 0; k < 6; ++k) win[a][b][k] = 0.f;
    {
#pragma unroll
        for (int dy = 0; dy < 3; ++dy) {
            int yy  = ty - 1 + dy;
            bool yok = (unsigned)yy < (unsigned)S;
            const float* rp = ip + yy * S;
            win[0][dy][0] = (yok && x0 > 0) ? rp[x0 - 1] : 0.f;
            float4 m = yok ? *(const float4*)(rp + x0) : float4{0.f, 0.f, 0.f, 0.f};
            win[0][dy][1] = m.x;
            win[0][dy][2] = m.y;
            win[0][dy][3] = m.z;
            win[0][dy][4] = m.w;
            win[0][dy][5] = (yok && (x0 + 4 < S)) ? rp[x0 + 4] : 0.f;
        }
    }
#pragma unroll 1
    for (int zb = 0; zb < S; zb += 3) {
        conv_step<S, 0>(ip, zb, ty, x0, wv, win, lam, sc, hf, op);
        if (zb + 1 < S) conv_step<S, 1>(ip, zb + 1, ty, x0, wv, win, lam, sc, hf, op);
        if (zb + 2 < S) conv_step<S, 2>(ip, zb + 2, ty, x0, wv, win, lam, sc, hf, op);
    }
}

// ========== Final: LDS-tiled base conv + level-1 idwt + level-0 idwt =======
// Block tile: 8 d-cells x 4 h-cells x 32 w-cells => outputs 16z x 8y x 64x.
// Thread: 4 w-consecutive cells (32 outputs). t0 read as float4/band
// (coalesced); t1 idwt folded into band 0 on the fly (replaces idwt_add_k).
__global__ __launch_bounds__(256, 3) void final_k2(
    const float* __restrict__ x, const float* __restrict__ t0,
    const float* __restrict__ t1, const float* __restrict__ bw,
    const float* __restrict__ bb, const float* __restrict__ bscale,
    float* __restrict__ out) {
    __shared__ float xs[18 * 10 * 67];
    int bx = blockIdx.x;
    int c  = bx >> 5;
    int ti = bx & 31;
    int dt = ti >> 3;  // z tile (16 thick)
    int ht = ti & 7;   // y tile (8 thick)
    const float* xc = x + ((long)c << 18);
    int zg0 = 16 * dt - 1, yg0 = 8 * ht - 1;
    for (int i = threadIdx.x; i < 18 * 10 * 66; i += 256) {
        int pz = i / 660;
        int r  = i - pz * 660;
        int py = r / 66;
        int px = r - py * 66;
        int zg = zg0 + pz, yg = yg0 + py, xg = px - 1;
        bool ok = ((unsigned)zg < 64u) && ((unsigned)yg < 64u) && ((unsigned)xg < 64u);
        xs[(pz * 10 + py) * 67 + px] = ok ? xc[(zg << 12) + (yg << 6) + xg] : 0.f;
    }
    const float* wp0 = bw + c * 27;
    float wv[27];
#pragma unroll
    for (int k = 0; k < 27; ++k) wv[k] = wp0[k];
    float bias = bb[c], scl = bscale[c];
    __syncthreads();

    int tid = threadIdx.x;
    int wc  = tid & 7;         // x chunk: cells w0..w0+3
    int hc  = (tid >> 3) & 3;  // h cell in tile
    int dc  = tid >> 5;        // d cell in tile
    int d   = dt * 8 + dc;
    int h   = ht * 4 + hc;
    int w0  = wc * 4;

    float acc[2][2][8];
#pragma unroll
    for (int oz = 0; oz < 2; ++oz)
#pragma unroll
        for (int oy = 0; oy < 2; ++oy)
#pragma unroll
            for (int m = 0; m < 8; ++m) acc[oz][oy][m] = 0.f;

#pragma unroll
    for (int pz = 0; pz < 4; ++pz) {
        float r[4][10];
#pragma unroll
        for (int py = 0; py < 4; ++py)
#pragma unroll
            for (int k = 0; k < 10; ++k)
                r[py][k] = xs[((2 * dc + pz) * 10 + (2 * hc + py)) * 67 + 8 * wc + k];
#pragma unroll
        for (int oz = 0; oz < 2; ++oz) {
            int kz = pz - oz;
            if (kz >= 0 && kz <= 2) {
#pragma unroll
                for (int py = 0; py < 4; ++py)
#pragma unroll
                    for (int oy = 0; oy < 2; ++oy) {
                        int ky = py - oy;
                        if (ky >= 0 && ky <= 2) {
#pragma unroll
                            for (int kx = 0; kx < 3; ++kx) {
                                float wgt = wv[kz * 9 + ky * 3 + kx];
#pragma unroll
                                for (int m = 0; m < 8; ++m)
                                    acc[oz][oy][m] += r[py][m + kx] * wgt;
                            }
                        }
                    }
            }
        }
    }

    // epilogue: t0 (float4/band) + t1 idwt into band0, haar_inv, store
    int cell0 = (d << 10) + (h << 5) + w0;
    float4 t0v[8];
#pragma unroll
    for (int f = 0; f < 8; ++f)
        t0v[f] = *(const float4*)(t0 + (((long)(c * 8 + f)) << 15) + cell0);
    int s1b = ((d >> 1) * 16 + (h >> 1)) * 16 + (w0 >> 1);
    float2 t1v[8];
#pragma unroll
    for (int f = 0; f < 8; ++f)
        t1v[f] = *(const float2*)(t1 + ((c * 8 + f) << 12) + s1b);

#pragma unroll
    for (int j = 0; j < 4; ++j) {
        int w = w0 + j;
        float tf[8];
#pragma unroll
        for (int f = 0; f < 8; ++f) tf[f] = ((const float*)&t0v[f])[j];
        float add = 0.f;
#pragma unroll
        for (int f = 0; f < 8; ++f) {
            float v  = (j >> 1) ? t1v[f].y : t1v[f].x;
            float sg = 1.f;
            if ((f & 4) && (d & 1)) sg = -sg;
            if ((f & 2) && (h & 1)) sg = -sg;
            if ((f & 1) && (j & 1)) sg = -sg;
            add += sg * v;
        }
        tf[0] += add * SQ3F;
        float contrib[8];
        haar_inv(tf, contrib);
#pragma unroll
        for (int oz = 0; oz < 2; ++oz)
#pragma unroll
            for (int oy = 0; oy < 2; ++oy) {
                float2 rr;
                rr.x = (acc[oz][oy][2 * j] + bias) * scl + contrib[oz * 4 + oy * 2];
                rr.y = (acc[oz][oy][2 * j + 1] + bias) * scl +
                       contrib[oz * 4 + oy * 2 + 1];
                *(float2*)(out + ((long)c << 18) + ((2 * d + oz) << 12) +
                           ((2 * h + oy) << 6) + 2 * w) = rr;
            }
    }
}

extern "C" void kernel_launch(void* const* d_in, const int* in_sizes, int n_in,
                              void* d_out, int out_size, void* d_ws, size_t ws_size,
                              hipStream_t stream) {
    const float* x      = (const float*)d_in[0];
    const float* base_w = (const float*)d_in[1];
    const float* base_b = (const float*)d_in[2];
    const float* base_s = (const float*)d_in[3];
    const float* w0     = (const float*)d_in[4];
    const float* w1     = (const float*)d_in[5];
    const float* ws0    = (const float*)d_in[6];
    const float* ws1    = (const float*)d_in[7];
    const float* lambd  = (const float*)d_in[8];
    float* out = (float*)d_out;

    // Workspace (floats): ll 2.1M | t0 16.8M | cx1 2.1M | t1 2.1M
    float* ll  = (float*)d_ws;
    float* t0  = ll + 2097152;
    float* cx1 = t0 + 16777216;
    float* t1  = cx1 + 2097152;

    // Level 0 fused: x -> t0 (conv+soft+scale, all 8 bands) + raw LL
    fused_l0_k<<<512, 512, 0, stream>>>(x, w0, ws0, lambd, t0, ll);
    // Level 1
    dwt3_k<16><<<1024, 256, 0, stream>>>(ll, 32768, cx1);
    dwconv_soft_roll_k<16, 4><<<128, 256, 0, stream>>>(cx1, w1, ws1, lambd, t1);
    // Final: base conv + level-1 idwt (fused) + level-0 idwt
    final_k2<<<2048, 256, 0, stream>>>(x, t0, t1, base_w, base_b, base_s, out);
}